// Round 1
// baseline (154.320 us; speedup 1.0000x reference)
//
#include <hip/hip_runtime.h>
#include <math.h>

// QuantumLayer: 4 qubits, 2 layers, B=524288.
//
// Fused single-kernel version. z_q = P^T C_q Q as before, but build_C4 now
// runs inside block 0 of the wide kernel; blocks 1..2047 overlap their x-load
// + P/Q transcendentals with the build, then wait on an agent-scope flag
// (programmatic dependent launch). Contraction path unchanged from the
// R1/R2-proven scalar v_fmac + merged s_load_dwordx4 structure: reads go
// through a separate const __restrict__ pointer (C4r) so uniform-load
// scalarization is not blocked by the block-0 stores (C4w).
//
// Safety:
//  - __launch_bounds__(256,8) -> VGPR<=64 -> 8 blocks/CU -> all 2048 blocks
//    co-resident -> spin cannot deadlock regardless of dispatch order.
//  - token is a per-capture host counter: graph replays reuse the captured
//    token; a pre-set flag then implies C4 already holds the identical
//    weight-derived values (C depends only on weights). Workspace re-poison
//    (the 256MiB fill seen in rocprof) resets the flag -> rebuild.

__global__ __launch_bounds__(256, 8) void qfused(
    const float* __restrict__ x,
    const float* __restrict__ weight,
    float* __restrict__ out,
    float4* __restrict__ C4w,        // write path (block 0)
    const float4* __restrict__ C4r,  // read path: uniform idx -> s_load_dwordx4
    int* __restrict__ flag,
    int token,
    int B)
{
    const int tid = threadIdx.x;
    const int s0 = blockIdx.x * 256 + tid;

    // Issue the sample load immediately (overlaps with build/spin).
    float4 xv = (s0 < B) ? reinterpret_cast<const float4*>(x)[s0]
                         : float4{0.f, 0.f, 0.f, 0.f};

    if (blockIdx.x == 0) {
        // ---- C build (identical math to the two-kernel build_C4) ----
        __shared__ float cw[16], sw[16];
        __shared__ float Ur[16][16], Ui[16][16];
        __shared__ float A[4][16][16];

        if (tid < 16) {
            float h = 0.5f * weight[tid];
            __sincosf(h, &sw[tid], &cw[tid]);
        }
        __syncthreads();

        if (tid < 16) {
            const int col = tid;
            float re[16], im[16];
            #pragma unroll
            for (int i = 0; i < 16; ++i) { re[i] = 0.f; im[i] = 0.f; }
            re[col] = 1.f;

            #pragma unroll
            for (int layer = 0; layer < 2; ++layer) {
                #pragma unroll
                for (int q = 0; q < 4; ++q) {
                    float cy = cw[layer*8 + q*2 + 0];
                    float sy = sw[layer*8 + q*2 + 0];
                    float cz = cw[layer*8 + q*2 + 1];
                    float sz = sw[layer*8 + q*2 + 1];
                    int st = 8 >> q;
                    #pragma unroll
                    for (int i = 0; i < 16; ++i) {
                        if (i & st) continue;
                        int j = i | st;
                        float r0 = re[i], r1 = re[j], i0 = im[i], i1 = im[j];
                        float nr0 = cy*r0 - sy*r1;
                        float nr1 = sy*r0 + cy*r1;
                        float ni0 = cy*i0 - sy*i1;
                        float ni1 = sy*i0 + cy*i1;
                        re[i] = nr0*cz + ni0*sz;
                        im[i] = ni0*cz - nr0*sz;
                        re[j] = nr1*cz - ni1*sz;
                        im[j] = ni1*cz + nr1*sz;
                    }
                }
                #pragma unroll
                for (int q = 0; q < 4; ++q) {
                    int cb = 8 >> q;
                    int tb = 8 >> ((q + 1) & 3);
                    #pragma unroll
                    for (int i = 0; i < 16; ++i) {
                        if ((i & cb) && !(i & tb)) {
                            int j = i | tb;
                            float tr = re[i]; re[i] = re[j]; re[j] = tr;
                            float ti = im[i]; im[i] = im[j]; im[j] = ti;
                        }
                    }
                }
            }
            #pragma unroll
            for (int i = 0; i < 16; ++i) { Ur[i][col] = re[i]; Ui[i][col] = im[i]; }
        }
        __syncthreads();

        for (int e = tid; e < 1024; e += 256) {
            int q = e >> 8, j = (e >> 4) & 15, k = e & 15;
            float sum = 0.f;
            for (int i = 0; i < 16; ++i) {
                float t = Ur[i][j]*Ur[i][k] + Ui[i][j]*Ui[i][k];
                sum += (i & (8 >> q)) ? -t : t;
            }
            A[q][j][k] = sum;
        }
        __syncthreads();

        if (tid < 100) {
            const int pu[10] = {0,0,0,0,1,1,1,2,2,3};
            const int pv[10] = {0,1,2,3,1,2,3,2,3,3};
            int pi = tid / 10, qi = tid % 10;
            int u = pu[pi], v = pv[pi], r = pu[qi], sI = pv[qi];
            int a1s[2] = {u, v}, a2s[2] = {v, u};
            int b1s[2] = {r, sI}, b2s[2] = {sI, r};
            int na = (u == v) ? 1 : 2;
            int nb = (r == sI) ? 1 : 2;
            float acc[4] = {0.f, 0.f, 0.f, 0.f};
            for (int ia = 0; ia < na; ++ia)
                for (int ib = 0; ib < nb; ++ib) {
                    int j = a1s[ia]*4 + b1s[ib];
                    int k = a2s[ia]*4 + b2s[ib];
                    #pragma unroll
                    for (int q = 0; q < 4; ++q) acc[q] += A[q][j][k];
                }
            C4w[tid] = float4{acc[0], acc[1], acc[2], acc[3]};
        }
        // Publish: every thread fences its own stores (agent scope), then one
        // release-store of the token after the barrier.
        __threadfence();
        __syncthreads();
        if (tid == 0)
            __hip_atomic_store(flag, token, __ATOMIC_RELEASE, __HIP_MEMORY_SCOPE_AGENT);
    }

    const int pu[10] = {0,0,0,0,1,1,1,2,2,3};
    const int pv[10] = {0,1,2,3,1,2,3,2,3,3};

    // Per-sample P/Q — overlaps with block 0's build for blocks 1..2047.
    float P[10], Q[10];
    {
        float xs[4] = {xv.x, xv.y, xv.z, xv.w};
        float c[4], s[4];
        #pragma unroll
        for (int q = 0; q < 4; ++q) {
            // angle = tanh(x)*pi/2 = pi/2 - pi*u, u = 1/(exp(2x)+1)
            //   cos(angle) = sin(pi*u) = v_sin(u/2)   [v_sin takes revolutions]
            //   sin(angle) = cos(pi*u) = v_cos(u/2)
            // arg in [0,0.5] rev -> no range reduction needed; limits x->±inf
            // give u->{0,1} -> exact (0,±1) endpoints. err ~1e-6 vs 2e-2 thr.
            float e = __expf(2.f * xs[q]);
            float uu = __builtin_amdgcn_rcpf(e + 1.f);
            float rr = 0.5f * uu;
            c[q] = __builtin_amdgcn_sinf(rr);
            s[q] = __builtin_amdgcn_cosf(rr);
        }
        float a4[4] = {c[0]*c[1], c[0]*s[1], s[0]*c[1], s[0]*s[1]};
        float b4[4] = {c[2]*c[3], c[2]*s[3], s[2]*c[3], s[2]*s[3]};
        #pragma unroll
        for (int i2 = 0; i2 < 10; ++i2) {
            P[i2] = a4[pu[i2]] * a4[pv[i2]];
            Q[i2] = b4[pu[i2]] * b4[pv[i2]];
        }
    }

    if (blockIdx.x != 0) {
        // Wait for C4. tid 0 polls with acquire (invalidates L1/L2 so the
        // subsequent s_loads observe fresh data); others park at the barrier.
        if (tid == 0) {
            while (__hip_atomic_load(flag, __ATOMIC_ACQUIRE, __HIP_MEMORY_SCOPE_AGENT) != token)
                __builtin_amdgcn_s_sleep(8);
        }
        __syncthreads();
    }

    // z_q = sum_pi P[pi] * (sum_qi C4[pi][qi][q] * Q[qi]) — pure scalar FMA,
    // coefficients arrive as SGPRs from merged s_load_dwordx4 (via C4r).
    float z0 = 0.f, z1 = 0.f, z2 = 0.f, z3 = 0.f;
    #pragma unroll
    for (int pi = 0; pi < 10; ++pi) {
        float t0 = 0.f, t1 = 0.f, t2 = 0.f, t3 = 0.f;
        #pragma unroll
        for (int qi = 0; qi < 10; ++qi) {
            float4 cv = C4r[pi*10 + qi];
            float qv = Q[qi];
            t0 = fmaf(cv.x, qv, t0);
            t1 = fmaf(cv.y, qv, t1);
            t2 = fmaf(cv.z, qv, t2);
            t3 = fmaf(cv.w, qv, t3);
        }
        float pvf = P[pi];
        z0 = fmaf(pvf, t0, z0);
        z1 = fmaf(pvf, t1, z1);
        z2 = fmaf(pvf, t2, z2);
        z3 = fmaf(pvf, t3, z3);
    }

    if (s0 < B)
        reinterpret_cast<float4*>(out)[s0] = float4{z0, z1, z2, z3};
}

extern "C" void kernel_launch(void* const* d_in, const int* in_sizes, int n_in,
                              void* d_out, int out_size, void* d_ws, size_t ws_size,
                              hipStream_t stream) {
    const float* x = (const float*)d_in[0];
    const float* w = (const float*)d_in[1];
    float* out = (float*)d_out;
    float4* C4 = (float4*)d_ws;                    // 100 float4 = 1600 B
    int* flag = (int*)((char*)d_ws + 4096);        // separate cache line
    int B = in_sizes[0] / 4;

    // Per-capture token: replays reuse the captured value; a new capture
    // (possibly new weights) gets a new token and forces a rebuild.
    static int token = 0x51000000;
    ++token;

    int grid = (B + 255) / 256;  // 2048 blocks, 1 sample/thread
    qfused<<<grid, 256, 0, stream>>>(x, w, out, C4, (const float4*)C4, flag, token, B);
}

// Round 2
// 70.792 us; speedup vs baseline: 2.1799x; 2.1799x over previous
//
#include <hip/hip_runtime.h>
#include <math.h>

// QuantumLayer: 4 qubits, 2 layers, B=524288.
//
// z_q = P^T C_q Q ; P/Q = 10 unordered pair-products of the two 4-dim real
// product-state factors (qubits 0,1 / 2,3). C = batch-uniform tensor from the
// weights, packed float4 C4[pi*10+qi] = {C0,C1,C2,C3} in d_ws.
//
// Structure locked by rounds 1-5 evidence (prev session) + R1 (this session):
//  - two kernels. R1's single-kernel fusion with an agent-scope flag spin
//    regressed 72->154 us: cross-XCD release/acquire propagation stalled the
//    whole grid ~100 us (VALUBusy 13%, HBM 4%). Do NOT re-attempt intra-kernel
//    producer-consumer on this part.
//  - 1 sample/thread, 2048 blocks (2/4-sample variants raise VGPRs: lost)
//  - scalar v_fmac chains with uniform-load coefficients (f32x2 "packed"
//    forms emitted mov-heavy code: lost; scalar won)
//  - coefficients via compile-time-uniform loads -> s_load_dwordx4 ([10][10][4]
//    float4 layout).
//  - qmain trig: angle = pi/2 - pi*u, u = 1/(exp(2x)+1);
//    cos(angle)=sin(pi*u)=v_sin(u/2), sin(angle)=cos(pi*u)=v_cos(u/2)
//    (v_sin/v_cos take revolutions; arg in [0,0.5] -> no range reduction).
//    Verified in R1 (absmax identical 0.00390625); removes the fdiv chain.

#define HALF_PI_F 1.57079632679489661923f

__global__ __launch_bounds__(256) void build_C4(
    const float* __restrict__ weight,
    float4* __restrict__ C4g)  // 100 float4: [pi][qi][q]
{
    __shared__ float cw[16], sw[16];
    __shared__ float Ur[16][16], Ui[16][16];
    __shared__ float A[4][16][16];

    const int tid = threadIdx.x;
    if (tid < 16) {
        float h = 0.5f * weight[tid];
        __sincosf(h, &sw[tid], &cw[tid]);
    }
    __syncthreads();

    if (tid < 16) {
        const int col = tid;
        float re[16], im[16];
        #pragma unroll
        for (int i = 0; i < 16; ++i) { re[i] = 0.f; im[i] = 0.f; }
        re[col] = 1.f;

        #pragma unroll
        for (int layer = 0; layer < 2; ++layer) {
            #pragma unroll
            for (int q = 0; q < 4; ++q) {
                float cy = cw[layer*8 + q*2 + 0];
                float sy = sw[layer*8 + q*2 + 0];
                float cz = cw[layer*8 + q*2 + 1];
                float sz = sw[layer*8 + q*2 + 1];
                int st = 8 >> q;
                #pragma unroll
                for (int i = 0; i < 16; ++i) {
                    if (i & st) continue;
                    int j = i | st;
                    float r0 = re[i], r1 = re[j], i0 = im[i], i1 = im[j];
                    float nr0 = cy*r0 - sy*r1;
                    float nr1 = sy*r0 + cy*r1;
                    float ni0 = cy*i0 - sy*i1;
                    float ni1 = sy*i0 + cy*i1;
                    re[i] = nr0*cz + ni0*sz;
                    im[i] = ni0*cz - nr0*sz;
                    re[j] = nr1*cz - ni1*sz;
                    im[j] = ni1*cz + nr1*sz;
                }
            }
            #pragma unroll
            for (int q = 0; q < 4; ++q) {
                int cb = 8 >> q;
                int tb = 8 >> ((q + 1) & 3);
                #pragma unroll
                for (int i = 0; i < 16; ++i) {
                    if ((i & cb) && !(i & tb)) {
                        int j = i | tb;
                        float tr = re[i]; re[i] = re[j]; re[j] = tr;
                        float ti = im[i]; im[i] = im[j]; im[j] = ti;
                    }
                }
            }
        }
        #pragma unroll
        for (int i = 0; i < 16; ++i) { Ur[i][col] = re[i]; Ui[i][col] = im[i]; }
    }
    __syncthreads();

    for (int e = tid; e < 1024; e += 256) {
        int q = e >> 8, j = (e >> 4) & 15, k = e & 15;
        float sum = 0.f;
        for (int i = 0; i < 16; ++i) {
            float t = Ur[i][j]*Ur[i][k] + Ui[i][j]*Ui[i][k];
            sum += (i & (8 >> q)) ? -t : t;
        }
        A[q][j][k] = sum;
    }
    __syncthreads();

    if (tid < 100) {
        const int pu[10] = {0,0,0,0,1,1,1,2,2,3};
        const int pv[10] = {0,1,2,3,1,2,3,2,3,3};
        int pi = tid / 10, qi = tid % 10;
        int u = pu[pi], v = pv[pi], r = pu[qi], sI = pv[qi];
        int a1s[2] = {u, v}, a2s[2] = {v, u};
        int b1s[2] = {r, sI}, b2s[2] = {sI, r};
        int na = (u == v) ? 1 : 2;
        int nb = (r == sI) ? 1 : 2;
        float acc[4] = {0.f, 0.f, 0.f, 0.f};
        for (int ia = 0; ia < na; ++ia)
            for (int ib = 0; ib < nb; ++ib) {
                int j = a1s[ia]*4 + b1s[ib];
                int k = a2s[ia]*4 + b2s[ib];
                #pragma unroll
                for (int q = 0; q < 4; ++q) acc[q] += A[q][j][k];
            }
        C4g[tid] = float4{acc[0], acc[1], acc[2], acc[3]};
    }
}

__global__ __launch_bounds__(256) void qmain(
    const float* __restrict__ x,
    const float4* __restrict__ C4g,  // uniform indices -> s_load_dwordx4
    float* __restrict__ out,
    int B)
{
    const int s0 = blockIdx.x * 256 + threadIdx.x;

    float4 xv = (s0 < B) ? reinterpret_cast<const float4*>(x)[s0]
                         : float4{0.f, 0.f, 0.f, 0.f};

    const int pu[10] = {0,0,0,0,1,1,1,2,2,3};
    const int pv[10] = {0,1,2,3,1,2,3,2,3,3};

    float P[10], Q[10];
    {
        float xs[4] = {xv.x, xv.y, xv.z, xv.w};
        float c[4], s[4];
        #pragma unroll
        for (int q = 0; q < 4; ++q) {
            // angle = tanh(x)*pi/2 = pi/2 - pi*u, u = 1/(exp(2x)+1)
            //   cos(angle) = sin(pi*u) = v_sin(u/2)   [v_sin takes revolutions]
            //   sin(angle) = cos(pi*u) = v_cos(u/2)
            // arg in [0,0.5] rev -> no range reduction; x->+-inf gives exact
            // (0,+-1) endpoints. Verified R1: absmax unchanged (0.0039).
            float e = __expf(2.f * xs[q]);
            float uu = __builtin_amdgcn_rcpf(e + 1.f);
            float rr = 0.5f * uu;
            c[q] = __builtin_amdgcn_sinf(rr);
            s[q] = __builtin_amdgcn_cosf(rr);
        }
        float a4[4] = {c[0]*c[1], c[0]*s[1], s[0]*c[1], s[0]*s[1]};
        float b4[4] = {c[2]*c[3], c[2]*s[3], s[2]*c[3], s[2]*s[3]};
        #pragma unroll
        for (int i2 = 0; i2 < 10; ++i2) {
            P[i2] = a4[pu[i2]] * a4[pv[i2]];
            Q[i2] = b4[pu[i2]] * b4[pv[i2]];
        }
    }

    // z_q = sum_pi P[pi] * (sum_qi C4[pi][qi][q] * Q[qi]) — pure scalar FMA,
    // coefficients arrive as SGPRs from merged s_load_dwordx4.
    float z0 = 0.f, z1 = 0.f, z2 = 0.f, z3 = 0.f;
    #pragma unroll
    for (int pi = 0; pi < 10; ++pi) {
        float t0 = 0.f, t1 = 0.f, t2 = 0.f, t3 = 0.f;
        #pragma unroll
        for (int qi = 0; qi < 10; ++qi) {
            float4 cv = C4g[pi*10 + qi];
            float qv = Q[qi];
            t0 = fmaf(cv.x, qv, t0);
            t1 = fmaf(cv.y, qv, t1);
            t2 = fmaf(cv.z, qv, t2);
            t3 = fmaf(cv.w, qv, t3);
        }
        float pvf = P[pi];
        z0 = fmaf(pvf, t0, z0);
        z1 = fmaf(pvf, t1, z1);
        z2 = fmaf(pvf, t2, z2);
        z3 = fmaf(pvf, t3, z3);
    }

    if (s0 < B)
        reinterpret_cast<float4*>(out)[s0] = float4{z0, z1, z2, z3};
}

extern "C" void kernel_launch(void* const* d_in, const int* in_sizes, int n_in,
                              void* d_out, int out_size, void* d_ws, size_t ws_size,
                              hipStream_t stream) {
    const float* x = (const float*)d_in[0];
    const float* w = (const float*)d_in[1];
    float* out = (float*)d_out;
    float4* C4g = (float4*)d_ws;  // 100 float4 = 1600 B
    int B = in_sizes[0] / 4;

    build_C4<<<1, 256, 0, stream>>>(w, C4g);
    int grid = (B + 255) / 256;  // 1 sample/thread, 256 threads/block
    qmain<<<grid, 256, 0, stream>>>(x, C4g, out, B);
}

// Round 3
// 68.714 us; speedup vs baseline: 2.2458x; 1.0302x over previous
//
#include <hip/hip_runtime.h>
#include <math.h>

// QuantumLayer: 4 qubits, 2 layers, B=524288.
//
// R3 restructure: z_q = sum_i sign_q(i) |psi_i|^2, psi = U s, computed with
// MFMA (v_mfma_f32_16x16x16f16) instead of the P^T C_q Q scalar contraction.
// Rationale (R1 calibration: graph-replay launch overhead ~0-3 us, so R2's
// 28.8 us non-fill time is mostly qmain): the old qmain re-issued ~100
// s_load_dwordx4 per wave (400 coeffs >> ~100 SGPR budget) -> scalar-memory
// bound at ~20 us vs a ~3.5 us VALU floor. MFMA keeps U in 4 VGPRs/lane,
// loaded once per wave.
//
//  - U (16x16 complex, batch-uniform) built by a 1-wave kernel, emitted
//    directly in f16 A-fragment layout: lane l holds A[m=l&15][k=(l>>4)*4+j],
//    j=0..3, packed 2 dwords re + 2 dwords im. (uint2 UF[128] in d_ws.)
//  - qmain: per wave, 64 samples. Each lane computes its own state vector
//    s[16] = a4[i>>2]*b4[i&3] (real, product state), packs f16 to LDS
//    (sample-major [256][16]); 4 sample-groups of 16: B-frag = ds_read_b64
//    at S[g*16 + (l&15)][(l>>4)*4]; 2 MFMAs (re,im); |psi|^2; signed sums;
//    8-shfl butterfly over lane bits 4,5; masked float4 store per group.
//  - C/D layout col=lane&15, row=(lane>>4)*4+reg (HW-verified, m89);
//    A row = lane&15, B col = lane&15, k-block = (lane>>4)*4 (standard
//    gfx908+ 16x16x16f16 mapping).
//  - trig path (R2-verified, absmax unchanged): angle = pi/2 - pi*u,
//    u = 1/(exp(2x)+1); cos=v_sin(u/2), sin=v_cos(u/2) (revolutions).
//  - R1 lesson kept: NO cross-block producer/consumer (flag spin regressed
//    72->154 us). Two kernels, same stream.

typedef _Float16 f16x4 __attribute__((ext_vector_type(4)));
typedef _Float16 f16x8 __attribute__((ext_vector_type(8)));
typedef float f32x4 __attribute__((ext_vector_type(4)));

static __device__ inline unsigned pk16(float a, float b) {
    unsigned short ua = __builtin_bit_cast(unsigned short, (_Float16)a);
    unsigned short ub = __builtin_bit_cast(unsigned short, (_Float16)b);
    return (unsigned)ua | ((unsigned)ub << 16);
}

__global__ __launch_bounds__(64) void build_U(
    const float* __restrict__ weight,
    uint2* __restrict__ UF)  // [0..63] = Ur frag, [64..127] = Ui frag
{
    __shared__ float cw[16], sw[16];
    __shared__ float Ur[16][16], Ui[16][16];

    const int tid = threadIdx.x;
    if (tid < 16) {
        float h = 0.5f * weight[tid];
        __sincosf(h, &sw[tid], &cw[tid]);
    }
    __syncthreads();

    if (tid < 16) {
        const int col = tid;
        float re[16], im[16];
        #pragma unroll
        for (int i = 0; i < 16; ++i) { re[i] = 0.f; im[i] = 0.f; }
        re[col] = 1.f;

        #pragma unroll
        for (int layer = 0; layer < 2; ++layer) {
            #pragma unroll
            for (int q = 0; q < 4; ++q) {
                float cy = cw[layer*8 + q*2 + 0];
                float sy = sw[layer*8 + q*2 + 0];
                float cz = cw[layer*8 + q*2 + 1];
                float sz = sw[layer*8 + q*2 + 1];
                int st = 8 >> q;
                #pragma unroll
                for (int i = 0; i < 16; ++i) {
                    if (i & st) continue;
                    int j = i | st;
                    float r0 = re[i], r1 = re[j], i0 = im[i], i1 = im[j];
                    float nr0 = cy*r0 - sy*r1;
                    float nr1 = sy*r0 + cy*r1;
                    float ni0 = cy*i0 - sy*i1;
                    float ni1 = sy*i0 + cy*i1;
                    re[i] = nr0*cz + ni0*sz;
                    im[i] = ni0*cz - nr0*sz;
                    re[j] = nr1*cz - ni1*sz;
                    im[j] = ni1*cz + nr1*sz;
                }
            }
            #pragma unroll
            for (int q = 0; q < 4; ++q) {
                int cb = 8 >> q;
                int tb = 8 >> ((q + 1) & 3);
                #pragma unroll
                for (int i = 0; i < 16; ++i) {
                    if ((i & cb) && !(i & tb)) {
                        int j = i | tb;
                        float tr = re[i]; re[i] = re[j]; re[j] = tr;
                        float ti = im[i]; im[i] = im[j]; im[j] = ti;
                    }
                }
            }
        }
        #pragma unroll
        for (int i = 0; i < 16; ++i) { Ur[i][col] = re[i]; Ui[i][col] = im[i]; }
    }
    __syncthreads();

    // Emit f16 A-fragments: lane l -> A[m = l&15][k = (l>>4)*4 + j].
    {
        int m = tid & 15, k0 = (tid >> 4) << 2;
        UF[tid]      = uint2{pk16(Ur[m][k0], Ur[m][k0+1]),
                             pk16(Ur[m][k0+2], Ur[m][k0+3])};
        UF[64 + tid] = uint2{pk16(Ui[m][k0], Ui[m][k0+1]),
                             pk16(Ui[m][k0+2], Ui[m][k0+3])};
    }
}

__global__ __launch_bounds__(256) void qmain(
    const float* __restrict__ x,
    const uint2* __restrict__ UF,
    float* __restrict__ out,
    int B)
{
    __shared__ _Float16 S[256][16];  // per-thread state vector, f16

    const int tid  = threadIdx.x;
    const int lane = tid & 63;
    const int s0   = blockIdx.x * 256 + tid;

    float4 xv = (s0 < B) ? reinterpret_cast<const float4*>(x)[s0]
                         : float4{0.f, 0.f, 0.f, 0.f};

    // A-fragments for this wave (all waves read the same hot 1 KB).
    uint2 ur2 = UF[lane];
    uint2 ui2 = UF[64 + lane];

    float c[4], s[4];
    {
        float xs[4] = {xv.x, xv.y, xv.z, xv.w};
        #pragma unroll
        for (int q = 0; q < 4; ++q) {
            // angle = tanh(x)*pi/2 = pi/2 - pi*u, u = 1/(exp(2x)+1)
            // cos(angle)=sin(pi*u)=v_sin(u/2), sin(angle)=cos(pi*u)=v_cos(u/2)
            // (v_sin/v_cos take revolutions; arg in [0,0.5]). R2-verified.
            float e = __expf(2.f * xs[q]);
            float uu = __builtin_amdgcn_rcpf(e + 1.f);
            float rr = 0.5f * uu;
            c[q] = __builtin_amdgcn_sinf(rr);
            s[q] = __builtin_amdgcn_cosf(rr);
        }
    }
    float a4[4] = {c[0]*c[1], c[0]*s[1], s[0]*c[1], s[0]*s[1]};
    float b4[4] = {c[2]*c[3], c[2]*s[3], s[2]*c[3], s[2]*s[3]};

    // s[i] = a4[i>>2] * b4[i&3], i = state index (q0=bit3 .. q3=bit0).
    f16x8 lo, hi;
    #pragma unroll
    for (int i = 0; i < 8; ++i)  lo[i] = (_Float16)(a4[i >> 2] * b4[i & 3]);
    #pragma unroll
    for (int i = 8; i < 16; ++i) hi[i - 8] = (_Float16)(a4[i >> 2] * b4[i & 3]);
    *reinterpret_cast<f16x8*>(&S[tid][0]) = lo;
    *reinterpret_cast<f16x8*>(&S[tid][8]) = hi;
    __syncthreads();

    f16x4 afr = __builtin_bit_cast(f16x4, ur2);
    f16x4 afi = __builtin_bit_cast(f16x4, ui2);

    const int lg = lane >> 4;        // lane-group = row-block of D
    const int n  = lane & 15;        // D column = sample-in-group
    const float sg1 = (lg & 1) ? -1.f : 1.f;   // Z_1 sign: i bit2 = lg&1
    const float sg0 = (lg & 2) ? -1.f : 1.f;   // Z_0 sign: i bit3 = lg>>1
    const int wrow = tid & 192;      // wave's LDS row base (wave_id*64)
    const int wbase = blockIdx.x * 256 + wrow;  // wave's sample base

    #pragma unroll
    for (int g = 0; g < 4; ++g) {
        // B-frag: lane l needs sample (g*16+n)'s s[k], k = lg*4..lg*4+3.
        f16x4 bf = *reinterpret_cast<const f16x4*>(&S[wrow + g*16 + n][lg << 2]);

        f32x4 zero = {0.f, 0.f, 0.f, 0.f};
        f32x4 dre = __builtin_amdgcn_mfma_f32_16x16x16f16(afr, bf, zero, 0, 0, 0);
        f32x4 dim = __builtin_amdgcn_mfma_f32_16x16x16f16(afi, bf, zero, 0, 0, 0);

        // lane holds psi rows m = lg*4 + r, r=0..3, for sample col n.
        float m0 = dre[0]*dre[0] + dim[0]*dim[0];
        float m1 = dre[1]*dre[1] + dim[1]*dim[1];
        float m2 = dre[2]*dre[2] + dim[2]*dim[2];
        float m3 = dre[3]*dre[3] + dim[3]*dim[3];

        // sign_q(i) = -1 if bit(3-q) of i set; i = lg*4 + r.
        float sum = (m0 + m1) + (m2 + m3);
        float z3 = (m0 - m1) + (m2 - m3);   // bit0 = r&1
        float z2 = (m0 + m1) - (m2 + m3);   // bit1 = r>>1
        float z1 = sg1 * sum;               // bit2 = lg&1
        float z0 = sg0 * sum;               // bit3 = lg>>1

        // reduce over lane bits 4,5 (the lg dimension)
        z0 += __shfl_xor(z0, 16); z0 += __shfl_xor(z0, 32);
        z1 += __shfl_xor(z1, 16); z1 += __shfl_xor(z1, 32);
        z2 += __shfl_xor(z2, 16); z2 += __shfl_xor(z2, 32);
        z3 += __shfl_xor(z3, 16); z3 += __shfl_xor(z3, 32);

        int samp = wbase + g*16 + n;
        if (lg == g && samp < B)
            reinterpret_cast<float4*>(out)[samp] = float4{z0, z1, z2, z3};
    }
}

extern "C" void kernel_launch(void* const* d_in, const int* in_sizes, int n_in,
                              void* d_out, int out_size, void* d_ws, size_t ws_size,
                              hipStream_t stream) {
    const float* x = (const float*)d_in[0];
    const float* w = (const float*)d_in[1];
    float* out = (float*)d_out;
    uint2* UF = (uint2*)d_ws;  // 128 uint2 = 1 KB
    int B = in_sizes[0] / 4;

    build_U<<<1, 64, 0, stream>>>(w, UF);
    int grid = (B + 255) / 256;
    qmain<<<grid, 256, 0, stream>>>(x, UF, out, B);
}

// Round 4
// 66.509 us; speedup vs baseline: 2.3203x; 1.0331x over previous
//
#include <hip/hip_runtime.h>
#include <math.h>

// QuantumLayer: 4 qubits, 2 layers, B=524288.
//
// R4: single fused kernel, no workspace.
//  - Per-block redundant U-build (16 lanes, ~1us dependent chain) replaces the
//    serial build kernel + launch gap. All 2048 blocks are co-resident, so the
//    redundant builds run concurrently: wall cost ~= one build latency.
//    (R1 lesson: NO cross-block producer/consumer — a flag spin regressed
//    72->154 us on cross-XCD release/acquire. Per-block redundancy is safe.)
//  - psi = U s via v_mfma_f32_16x16x16f16 (R3-verified layout:
//    A: lane l holds A[m=l&15][k=(l>>4)*4+j]; B: B[k=(l>>4)*4+j][n=l&15];
//    D: D[row=(l>>4)*4+r][col=l&15], m89-verified).
//  - NEW: signed reduction z_q = sum_i sign_q(i)|psi_i|^2 done by a SECOND
//    MFMA with A = sign matrix (+-1 in rows 0..3, 0 elsewhere): the |psi|^2
//    values computed from D are already in B-fragment layout (D row/reg ==
//    B k/reg, col==col), so they feed straight in after f32->f16 cvt.
//    Replaces the 32-shfl butterfly + masked combine of R3. Lanes 0..15 get
//    {z0..z3} for one sample each in D regs 0..3 -> direct float4 store.
//    Precision: M<=1 via f16, f32 accum, 16 terms -> adds <=~4e-3 abs err
//    (threshold 2e-2; R3 absmax 0.0039).
//  - trig path (R2-verified): angle = pi/2 - pi*u, u = 1/(exp(2x)+1);
//    cos(angle)=v_sin(u/2), sin(angle)=v_cos(u/2) (revolutions, arg in
//    [0,0.5] -> no range reduction).
//  - LDS staging k-major S2[4][256] (8B elems): ds_write_b64/ds_read_b64 at
//    the 4-way floor for 64 lanes x 8B (m136: bank-conflict floor).

typedef _Float16 f16x4 __attribute__((ext_vector_type(4)));
typedef float f32x4 __attribute__((ext_vector_type(4)));

__global__ __launch_bounds__(256, 8) void qfused(
    const float* __restrict__ x,
    const float* __restrict__ weight,
    float* __restrict__ out,
    int B)
{
    __shared__ float Ur[16][16], Ui[16][16];
    __shared__ f16x4 S2[4][256];   // k-major: S2[kblk][sample_in_block]

    const int tid  = threadIdx.x;
    const int lane = tid & 63;
    const int s0   = blockIdx.x * 256 + tid;

    float4 xv = (s0 < B) ? reinterpret_cast<const float4*>(x)[s0]
                         : float4{0.f, 0.f, 0.f, 0.f};

    // ---- per-sample state vector (all threads) ----
    float c[4], s[4];
    {
        float xs[4] = {xv.x, xv.y, xv.z, xv.w};
        #pragma unroll
        for (int q = 0; q < 4; ++q) {
            float e = __expf(2.f * xs[q]);
            float uu = __builtin_amdgcn_rcpf(e + 1.f);
            float rr = 0.5f * uu;
            c[q] = __builtin_amdgcn_sinf(rr);
            s[q] = __builtin_amdgcn_cosf(rr);
        }
    }
    float a4[4] = {c[0]*c[1], c[0]*s[1], s[0]*c[1], s[0]*s[1]};
    float b4[4] = {c[2]*c[3], c[2]*s[3], s[2]*c[3], s[2]*s[3]};

    // s[i] = a4[i>>2]*b4[i&3]; store k-major, 4x ds_write_b64.
    #pragma unroll
    for (int j = 0; j < 4; ++j) {
        f16x4 sv;
        #pragma unroll
        for (int e = 0; e < 4; ++e) {
            int i = j*4 + e;
            sv[e] = (_Float16)(a4[i >> 2] * b4[i & 3]);
        }
        S2[j][tid] = sv;
    }

    // ---- per-block redundant U build (16 lanes of wave 0) ----
    if (tid < 16) {
        const int col = tid;
        float re[16], im[16];
        #pragma unroll
        for (int i = 0; i < 16; ++i) { re[i] = 0.f; im[i] = 0.f; }
        re[col] = 1.f;

        #pragma unroll
        for (int layer = 0; layer < 2; ++layer) {
            #pragma unroll
            for (int q = 0; q < 4; ++q) {
                // weight loads are uniform -> s_load; sincos computed on the
                // fly (uniform across the 16 builder lanes, 4 live temps).
                float cy, sy, cz, sz;
                __sincosf(0.5f * weight[layer*8 + q*2 + 0], &sy, &cy);
                __sincosf(0.5f * weight[layer*8 + q*2 + 1], &sz, &cz);
                int st = 8 >> q;
                #pragma unroll
                for (int i = 0; i < 16; ++i) {
                    if (i & st) continue;
                    int j = i | st;
                    float r0 = re[i], r1 = re[j], i0 = im[i], i1 = im[j];
                    float nr0 = cy*r0 - sy*r1;
                    float nr1 = sy*r0 + cy*r1;
                    float ni0 = cy*i0 - sy*i1;
                    float ni1 = sy*i0 + cy*i1;
                    re[i] = nr0*cz + ni0*sz;
                    im[i] = ni0*cz - nr0*sz;
                    re[j] = nr1*cz - ni1*sz;
                    im[j] = ni1*cz + nr1*sz;
                }
            }
            #pragma unroll
            for (int q = 0; q < 4; ++q) {
                int cb = 8 >> q;
                int tb = 8 >> ((q + 1) & 3);
                #pragma unroll
                for (int i = 0; i < 16; ++i) {
                    if ((i & cb) && !(i & tb)) {
                        int j = i | tb;
                        float tr = re[i]; re[i] = re[j]; re[j] = tr;
                        float ti = im[i]; im[i] = im[j]; im[j] = ti;
                    }
                }
            }
        }
        #pragma unroll
        for (int i = 0; i < 16; ++i) { Ur[i][col] = re[i]; Ui[i][col] = im[i]; }
    }
    __syncthreads();

    // ---- A-fragments: U (f16) and sign matrix ----
    const int m  = lane & 15;
    const int k0 = (lane >> 4) << 2;
    f16x4 afr, afi, As;
    #pragma unroll
    for (int j = 0; j < 4; ++j) {
        afr[j] = (_Float16)Ur[m][k0 + j];
        afi[j] = (_Float16)Ui[m][k0 + j];
        // sign_q(i) for q=m<4, state i=k0+j: -1 if bit(3-q) set.
        float sgn = (m < 4) ? ((((k0 + j) >> (3 - m)) & 1) ? -1.f : 1.f) : 0.f;
        As[j] = (_Float16)sgn;
    }

    const int n     = lane & 15;
    const int lg    = lane >> 4;
    const int wrow  = tid & 192;                   // wave's sample base in block
    const int wbase = blockIdx.x * 256 + wrow;

    #pragma unroll
    for (int g = 0; g < 4; ++g) {
        f16x4 bf = S2[lg][wrow + g*16 + n];

        f32x4 zero = {0.f, 0.f, 0.f, 0.f};
        f32x4 dre = __builtin_amdgcn_mfma_f32_16x16x16f16(afr, bf, zero, 0, 0, 0);
        f32x4 dim = __builtin_amdgcn_mfma_f32_16x16x16f16(afi, bf, zero, 0, 0, 0);

        // M[i][n] = |psi_i|^2, already in B-frag layout for the sign MFMA.
        f16x4 mb;
        #pragma unroll
        for (int r = 0; r < 4; ++r)
            mb[r] = (_Float16)(dre[r]*dre[r] + dim[r]*dim[r]);

        f32x4 zv = __builtin_amdgcn_mfma_f32_16x16x16f16(As, mb, zero, 0, 0, 0);

        // D rows 0..3 (z0..z3) live in lanes 0..15, regs 0..3.
        int samp = wbase + g*16 + lane;
        if (lane < 16 && samp < B)
            reinterpret_cast<float4*>(out)[samp] = float4{zv[0], zv[1], zv[2], zv[3]};
    }
}

extern "C" void kernel_launch(void* const* d_in, const int* in_sizes, int n_in,
                              void* d_out, int out_size, void* d_ws, size_t ws_size,
                              hipStream_t stream) {
    const float* x = (const float*)d_in[0];
    const float* w = (const float*)d_in[1];
    float* out = (float*)d_out;
    int B = in_sizes[0] / 4;

    int grid = (B + 255) / 256;  // 2048 blocks, 1 sample/thread
    qfused<<<grid, 256, 0, stream>>>(x, w, out, B);
}